// Round 1
// baseline (912.100 us; speedup 1.0000x reference)
//
#include <hip/hip_runtime.h>
#include <math.h>

#define H 1024
#define Nn 1024
#define Bb 64
#define Tt 256
#define BT (Bb * Tt)   // 16384

// ---------------- helpers ----------------

__device__ __forceinline__ float block_reduce_sum_256(float v) {
    __shared__ float sbuf[4];
    __syncthreads();                       // protect sbuf reuse across calls
    #pragma unroll
    for (int off = 32; off > 0; off >>= 1) v += __shfl_down(v, off, 64);
    int lane = threadIdx.x & 63, w = threadIdx.x >> 6;
    if (lane == 0) sbuf[w] = v;
    __syncthreads();
    if (threadIdx.x == 0) {
        float s = sbuf[0] + sbuf[1] + sbuf[2] + sbuf[3];
        sbuf[0] = s;
    }
    __syncthreads();
    return sbuf[0];
}

// ---------------- small kernels ----------------

// h_gate[b,h] = mean_t h_time[b,t,h].  grid(4, 64) x 256
__global__ void k_hgate(const float* __restrict__ h_time, float* __restrict__ h_gate) {
    int b = blockIdx.y;
    int col = blockIdx.x * 256 + threadIdx.x;
    float s = 0.f;
    const float* p = h_time + (size_t)b * Tt * H + col;
    for (int t = 0; t < Tt; ++t) s += p[(size_t)t * H];
    h_gate[b * H + col] = s * (1.0f / Tt);
}

// h_mean[h] = mean_b h_gate[b,h].  grid(4) x 256
__global__ void k_hmean(const float* __restrict__ h_gate, float* __restrict__ h_mean) {
    int h = blockIdx.x * 256 + threadIdx.x;
    float s = 0.f;
    for (int b = 0; b < Bb; ++b) s += h_gate[b * H + h];
    h_mean[h] = s * (1.0f / Bb);
}

// E_cur[n,:] = normalize(E_dyn[n,:] + h_mean).  grid(1024) x 256
__global__ void k_ecur(const float* __restrict__ E_dyn, const float* __restrict__ h_mean,
                       float* __restrict__ E_cur) {
    int n = blockIdx.x;
    float e[4]; float ss = 0.f;
    #pragma unroll
    for (int q = 0; q < 4; ++q) {
        int h = threadIdx.x + 256 * q;
        e[q] = E_dyn[(size_t)n * H + h] + h_mean[h];
        ss += e[q] * e[q];
    }
    float tot = block_reduce_sum_256(ss);
    float nrm = sqrtf(tot);
    float scale = 1.0f / fmaxf(nrm, 1e-12f);
    #pragma unroll
    for (int q = 0; q < 4; ++q) {
        int h = threadIdx.x + 256 * q;
        E_cur[(size_t)n * H + h] = e[q] * scale;
    }
}

// inv_r[i] = 1/(sum_j S[i,j] + 1e-6).  grid(1024) x 256
__global__ void k_invr(const float* __restrict__ S, float* __restrict__ inv_r) {
    int i = blockIdx.x;
    float s = 0.f;
    #pragma unroll
    for (int q = 0; q < 4; ++q) s += S[(size_t)i * Nn + threadIdx.x + 256 * q];
    float tot = block_reduce_sum_256(s);
    if (threadIdx.x == 0) inv_r[i] = 1.0f / (tot + 1e-6f);
}

// hid[b,j] = gelu(h_gate[b,:] @ W1[:,j] + b1[j]).  grid(64) x 512
__global__ void k_gate1(const float* __restrict__ h_gate, const float* __restrict__ W1,
                        const float* __restrict__ b1, float* __restrict__ hid) {
    __shared__ float sh[H];
    int b = blockIdx.x;
    sh[threadIdx.x] = h_gate[b * H + threadIdx.x];
    sh[threadIdx.x + 512] = h_gate[b * H + threadIdx.x + 512];
    __syncthreads();
    int j = threadIdx.x;
    float acc = b1[j];
    for (int k = 0; k < H; ++k) acc = fmaf(sh[k], W1[(size_t)k * 512 + j], acc);
    // exact GELU
    float g = 0.5f * acc * (1.0f + erff(acc * 0.70710678118654752f));
    hid[b * 512 + j] = g;
}

// gamma[b,n] = sigmoid(hid[b,:] @ W2[:,n] + b2[n]).  grid(64) x 1024
__global__ void k_gate2(const float* __restrict__ hid, const float* __restrict__ W2,
                        const float* __restrict__ b2, float* __restrict__ gamma) {
    __shared__ float sh[512];
    int b = blockIdx.x;
    if (threadIdx.x < 512) sh[threadIdx.x] = hid[b * 512 + threadIdx.x];
    __syncthreads();
    int n = threadIdx.x;
    float acc = b2[n];
    for (int k = 0; k < 512; ++k) acc = fmaf(sh[k], W2[(size_t)k * Nn + n], acc);
    gamma[b * Nn + n] = 1.0f / (1.0f + expf(-acc));
}

// gmean[n] = mean_b gamma[b,n].  grid(4) x 256
__global__ void k_gmean(const float* __restrict__ gamma, float* __restrict__ gmean) {
    int n = blockIdx.x * 256 + threadIdx.x;
    float s = 0.f;
    for (int b = 0; b < Bb; ++b) s += gamma[b * Nn + n];
    gmean[n] = s * (1.0f / Bb);
}

// A_mix[i,j] = gmean[i] * (alpha*A_p[i,j] + (1-alpha)*0.5*S[i,j]*(inv_r[i]+inv_r[j]))
// grid(1024) x 256
__global__ void k_amix(const float* __restrict__ S, const float* __restrict__ A_p,
                       const float* __restrict__ inv_r, const float* __restrict__ gmean,
                       const float* __restrict__ alpha_raw, float* __restrict__ A_mix) {
    int i = blockIdx.x;
    float alpha = 1.0f / (1.0f + expf(-alpha_raw[0]));
    float gm = gmean[i];
    float iri = inv_r[i];
    #pragma unroll
    for (int q = 0; q < 4; ++q) {
        int j = threadIdx.x + 256 * q;
        size_t idx = (size_t)i * Nn + j;
        float ad = 0.5f * S[idx] * (iri + inv_r[j]);
        A_mix[idx] = gm * fmaf(alpha, A_p[idx], (1.0f - alpha) * ad);
    }
}

// bias_h[h] = sum_n h2n_b[n]*C1[n,h] + n2h_b[h].  grid(4) x 256
__global__ void k_biash(const float* __restrict__ h2n_b, const float* __restrict__ C1,
                        const float* __restrict__ n2h_b, float* __restrict__ bias_h) {
    int h = blockIdx.x * 256 + threadIdx.x;
    float s = n2h_b[h];
    for (int n = 0; n < Nn; ++n) s = fmaf(h2n_b[n], C1[(size_t)n * H + h], s);
    bias_h[h] = s;
}

// ---------------- GEMM 64x64x16 (for 1024^3 GEMMs) ----------------
// C[M,N] = op(A) @ op(B);  op(A)[m,k] = TA ? A[k*M+m] : A[m*K+k]
//                          op(B)[k,n] = TB ? B[n*K+k] : B[k*N+n]
template <bool TA, bool TB, bool RELU>
__global__ __launch_bounds__(256) void gemm64(const float* __restrict__ A,
                                              const float* __restrict__ B,
                                              float* __restrict__ C,
                                              int M, int N, int K) {
    __shared__ float As[16][68];
    __shared__ float Bs[16][68];
    int tid = threadIdx.x;
    int n0 = blockIdx.x * 64, m0 = blockIdx.y * 64;
    int tx = tid & 15, ty = tid >> 4;
    float acc[4][4] = {};
    for (int k0 = 0; k0 < K; k0 += 16) {
        if (!TA) {
            int m = tid >> 2, k = (tid & 3) * 4;
            float4 v = *(const float4*)(A + (size_t)(m0 + m) * K + k0 + k);
            As[k + 0][m] = v.x; As[k + 1][m] = v.y; As[k + 2][m] = v.z; As[k + 3][m] = v.w;
        } else {
            int kk = tid >> 4, m = (tid & 15) * 4;
            float4 v = *(const float4*)(A + (size_t)(k0 + kk) * M + m0 + m);
            *(float4*)&As[kk][m] = v;
        }
        if (!TB) {
            int kk = tid >> 4, n = (tid & 15) * 4;
            float4 v = *(const float4*)(B + (size_t)(k0 + kk) * N + n0 + n);
            *(float4*)&Bs[kk][n] = v;
        } else {
            int n = tid >> 2, k = (tid & 3) * 4;
            float4 v = *(const float4*)(B + (size_t)(n0 + n) * K + k0 + k);
            Bs[k + 0][n] = v.x; Bs[k + 1][n] = v.y; Bs[k + 2][n] = v.z; Bs[k + 3][n] = v.w;
        }
        __syncthreads();
        #pragma unroll
        for (int k = 0; k < 16; ++k) {
            float a[4], b[4];
            #pragma unroll
            for (int i = 0; i < 4; ++i) a[i] = As[k][ty * 4 + i];
            #pragma unroll
            for (int j = 0; j < 4; ++j) b[j] = Bs[k][tx * 4 + j];
            #pragma unroll
            for (int i = 0; i < 4; ++i)
                #pragma unroll
                for (int j = 0; j < 4; ++j)
                    acc[i][j] = fmaf(a[i], b[j], acc[i][j]);
        }
        __syncthreads();
    }
    #pragma unroll
    for (int i = 0; i < 4; ++i) {
        int m = m0 + ty * 4 + i;
        float4 v;
        v.x = acc[i][0]; v.y = acc[i][1]; v.z = acc[i][2]; v.w = acc[i][3];
        if (RELU) {
            v.x = fmaxf(v.x, 0.f); v.y = fmaxf(v.y, 0.f);
            v.z = fmaxf(v.z, 0.f); v.w = fmaxf(v.w, 0.f);
        }
        *(float4*)(C + (size_t)m * N + n0 + tx * 4) = v;
    }
}

// ---------------- GEMM 128x128x8 NN + bias (msg = h_time @ C2 + bias_h) ----------------
__global__ __launch_bounds__(256) void gemm128_nn_bias(const float* __restrict__ A,
                                                       const float* __restrict__ B,
                                                       const float* __restrict__ bias,
                                                       float* __restrict__ C,
                                                       int M, int N, int K) {
    __shared__ float As[8][132];
    __shared__ float Bs[8][132];
    int tid = threadIdx.x;
    int n0 = blockIdx.x * 128, m0 = blockIdx.y * 128;
    int tx = tid & 15, ty = tid >> 4;
    float acc[8][8] = {};
    int am = tid >> 1, ak = (tid & 1) * 4;
    int bk = tid >> 5, bn = (tid & 31) * 4;
    const float* Aptr = A + (size_t)(m0 + am) * K + ak;
    for (int k0 = 0; k0 < K; k0 += 8) {
        float4 av = *(const float4*)(Aptr + k0);
        float4 bv = *(const float4*)(B + (size_t)(k0 + bk) * N + n0 + bn);
        As[ak + 0][am] = av.x; As[ak + 1][am] = av.y; As[ak + 2][am] = av.z; As[ak + 3][am] = av.w;
        *(float4*)&Bs[bk][bn] = bv;
        __syncthreads();
        #pragma unroll
        for (int k = 0; k < 8; ++k) {
            float a[8], b[8];
            #pragma unroll
            for (int i = 0; i < 8; ++i) a[i] = As[k][ty * 8 + i];
            #pragma unroll
            for (int j = 0; j < 8; ++j) b[j] = Bs[k][tx * 8 + j];
            #pragma unroll
            for (int i = 0; i < 8; ++i)
                #pragma unroll
                for (int j = 0; j < 8; ++j)
                    acc[i][j] = fmaf(a[i], b[j], acc[i][j]);
        }
        __syncthreads();
    }
    #pragma unroll
    for (int i = 0; i < 8; ++i) {
        int m = m0 + ty * 8 + i;
        float* Crow = C + (size_t)m * N + n0;
        #pragma unroll
        for (int j = 0; j < 8; j += 4) {
            int n = tx * 8 + j;
            float4 v;
            v.x = acc[i][j + 0] + bias[n0 + n + 0];
            v.y = acc[i][j + 1] + bias[n0 + n + 1];
            v.z = acc[i][j + 2] + bias[n0 + n + 2];
            v.w = acc[i][j + 3] + bias[n0 + n + 3];
            *(float4*)(Crow + n) = v;
        }
    }
}

// ---------------- final: y = h_time*(1+tanh(1/N)) + msg; LayerNorm; in-place on out ----------------
// grid(16384) x 256.  msg currently lives in `out`.
__global__ void k_final_ln(const float* __restrict__ h_time, const float* __restrict__ ln_w,
                           const float* __restrict__ ln_b, float* __restrict__ out) {
    size_t row = blockIdx.x;
    const float gw = tanhf(1.0f / (float)Nn);
    const float scale = 1.0f + gw;
    float y[4];
    float s = 0.f;
    #pragma unroll
    for (int q = 0; q < 4; ++q) {
        int h = threadIdx.x + 256 * q;
        y[q] = fmaf(h_time[row * H + h], scale, out[row * H + h]);
        s += y[q];
    }
    float mu = block_reduce_sum_256(s) * (1.0f / H);
    float ss = 0.f;
    #pragma unroll
    for (int q = 0; q < 4; ++q) {
        float d = y[q] - mu;
        ss += d * d;
    }
    float var = block_reduce_sum_256(ss) * (1.0f / H);
    float rstd = rsqrtf(var + 1e-5f);
    #pragma unroll
    for (int q = 0; q < 4; ++q) {
        int h = threadIdx.x + 256 * q;
        out[row * H + h] = fmaf((y[q] - mu) * rstd, ln_w[h], ln_b[h]);
    }
}

// ---------------- launch ----------------

extern "C" void kernel_launch(void* const* d_in, const int* in_sizes, int n_in,
                              void* d_out, int out_size, void* d_ws, size_t ws_size,
                              hipStream_t stream) {
    const float* h_time    = (const float*)d_in[0];
    const float* A_p       = (const float*)d_in[1];
    const float* E_dyn     = (const float*)d_in[2];
    const float* alpha_raw = (const float*)d_in[3];
    // d_in[4] = tau_raw: unused (attention branch is a constant)
    const float* gW1   = (const float*)d_in[5];
    const float* gb1   = (const float*)d_in[6];
    const float* gW2   = (const float*)d_in[7];
    const float* gb2   = (const float*)d_in[8];
    const float* h2n_W = (const float*)d_in[9];
    const float* h2n_b = (const float*)d_in[10];
    const float* n2h_W = (const float*)d_in[11];
    const float* n2h_b = (const float*)d_in[12];
    const float* ln_w  = (const float*)d_in[13];
    const float* ln_b  = (const float*)d_in[14];
    float* out = (float*)d_out;

    float* ws = (float*)d_ws;
    float* h_gate = ws;  ws += Bb * H;        // 65536
    float* h_mean = ws;  ws += H;             // 1024
    float* E_cur  = ws;  ws += Nn * H;        // 1M
    float* S      = ws;  ws += Nn * Nn;       // 1M
    float* inv_r  = ws;  ws += Nn;            // 1024
    float* hid    = ws;  ws += Bb * 512;      // 32768
    float* gamma  = ws;  ws += Bb * Nn;       // 65536
    float* gmean  = ws;  ws += Nn;            // 1024
    float* A_mix  = ws;  ws += Nn * Nn;       // 1M
    float* C1     = ws;  ws += Nn * H;        // 1M
    float* C2     = ws;  ws += H * H;         // 1M
    float* bias_h = ws;  ws += H;             // 1024

    // --- means ---
    k_hgate<<<dim3(4, 64), 256, 0, stream>>>(h_time, h_gate);
    k_hmean<<<4, 256, 0, stream>>>(h_gate, h_mean);

    // --- E path: E_cur, S = relu(E_cur E_cur^T), inv_r ---
    k_ecur<<<1024, 256, 0, stream>>>(E_dyn, h_mean, E_cur);
    gemm64<false, true, true><<<dim3(16, 16), 256, 0, stream>>>(E_cur, E_cur, S, Nn, Nn, H);
    k_invr<<<1024, 256, 0, stream>>>(S, inv_r);

    // --- gate MLP -> gamma_mean ---
    k_gate1<<<64, 512, 0, stream>>>(h_gate, gW1, gb1, hid);
    k_gate2<<<64, 1024, 0, stream>>>(hid, gW2, gb2, gamma);
    k_gmean<<<4, 256, 0, stream>>>(gamma, gmean);

    // --- A_mix ---
    k_amix<<<1024, 256, 0, stream>>>(S, A_p, inv_r, gmean, alpha_raw, A_mix);

    // --- collapsed weight chain: C1 = A_mix^T @ n2h_W; C2 = h2n_W @ C1 ---
    gemm64<true, false, false><<<dim3(16, 16), 256, 0, stream>>>(A_mix, n2h_W, C1, Nn, H, Nn);
    gemm64<false, false, false><<<dim3(16, 16), 256, 0, stream>>>(h2n_W, C1, C2, H, H, Nn);
    k_biash<<<4, 256, 0, stream>>>(h2n_b, C1, n2h_b, bias_h);

    // --- msg = h_time @ C2 + bias_h  (written into d_out) ---
    gemm128_nn_bias<<<dim3(8, 128), 256, 0, stream>>>(h_time, C2, bias_h, out, BT, H, H);

    // --- y = h_time*(1+tanh(1/N)) + msg; LayerNorm (in-place on out) ---
    k_final_ln<<<BT, 256, 0, stream>>>(h_time, ln_w, ln_b, out);
}

// Round 2
// 566.910 us; speedup vs baseline: 1.6089x; 1.6089x over previous
//
#include <hip/hip_runtime.h>
#include <math.h>

#define H 1024
#define Nn 1024
#define Bb 64
#define Tt 256
#define BT (Bb * Tt)   // 16384

// ---------------- helpers ----------------

__device__ __forceinline__ float block_reduce_sum_256(float v) {
    __shared__ float sbuf[4];
    __syncthreads();                       // protect sbuf reuse across calls
    #pragma unroll
    for (int off = 32; off > 0; off >>= 1) v += __shfl_down(v, off, 64);
    int lane = threadIdx.x & 63, w = threadIdx.x >> 6;
    if (lane == 0) sbuf[w] = v;
    __syncthreads();
    if (threadIdx.x == 0) {
        float s = sbuf[0] + sbuf[1] + sbuf[2] + sbuf[3];
        sbuf[0] = s;
    }
    __syncthreads();
    return sbuf[0];
}

__device__ __forceinline__ unsigned short f2bf(float x) {
    union { float f; unsigned u; } v; v.f = x;
    unsigned r = v.u + 0x7FFFu + ((v.u >> 16) & 1u);   // RNE
    return (unsigned short)(r >> 16);
}

typedef __attribute__((ext_vector_type(8))) short bf16x8;
typedef __attribute__((ext_vector_type(4))) float f32x4;

// ---------------- small kernels ----------------

// h_gate[b,h] = mean_t h_time[b,t,h]; also emit bf16 copy of h_time.  grid(4, 64) x 256
__global__ void k_hgate(const float* __restrict__ h_time, float* __restrict__ h_gate,
                        unsigned short* __restrict__ ht_bf16) {
    int b = blockIdx.y;
    int col = blockIdx.x * 256 + threadIdx.x;
    float s = 0.f;
    const size_t base = (size_t)b * Tt * H + col;
    for (int t = 0; t < Tt; ++t) {
        float v = h_time[base + (size_t)t * H];
        s += v;
        ht_bf16[base + (size_t)t * H] = f2bf(v);
    }
    h_gate[b * H + col] = s * (1.0f / Tt);
}

// h_mean[h] = mean_b h_gate[b,h].  grid(4) x 256
__global__ void k_hmean(const float* __restrict__ h_gate, float* __restrict__ h_mean) {
    int h = blockIdx.x * 256 + threadIdx.x;
    float s = 0.f;
    for (int b = 0; b < Bb; ++b) s += h_gate[b * H + h];
    h_mean[h] = s * (1.0f / Bb);
}

// E_cur[n,:] = normalize(E_dyn[n,:] + h_mean).  grid(1024) x 256
__global__ void k_ecur(const float* __restrict__ E_dyn, const float* __restrict__ h_mean,
                       float* __restrict__ E_cur) {
    int n = blockIdx.x;
    float e[4]; float ss = 0.f;
    #pragma unroll
    for (int q = 0; q < 4; ++q) {
        int h = threadIdx.x + 256 * q;
        e[q] = E_dyn[(size_t)n * H + h] + h_mean[h];
        ss += e[q] * e[q];
    }
    float tot = block_reduce_sum_256(ss);
    float nrm = sqrtf(tot);
    float scale = 1.0f / fmaxf(nrm, 1e-12f);
    #pragma unroll
    for (int q = 0; q < 4; ++q) {
        int h = threadIdx.x + 256 * q;
        E_cur[(size_t)n * H + h] = e[q] * scale;
    }
}

// inv_r[i] = 1/(sum_j S[i,j] + 1e-6).  grid(1024) x 256
__global__ void k_invr(const float* __restrict__ S, float* __restrict__ inv_r) {
    int i = blockIdx.x;
    float s = 0.f;
    #pragma unroll
    for (int q = 0; q < 4; ++q) s += S[(size_t)i * Nn + threadIdx.x + 256 * q];
    float tot = block_reduce_sum_256(s);
    if (threadIdx.x == 0) inv_r[i] = 1.0f / (tot + 1e-6f);
}

// hid[b,j] = gelu(h_gate[b,:] @ W1[:,j] + b1[j]).  grid(64) x 512
__global__ void k_gate1(const float* __restrict__ h_gate, const float* __restrict__ W1,
                        const float* __restrict__ b1, float* __restrict__ hid) {
    __shared__ float sh[H];
    int b = blockIdx.x;
    sh[threadIdx.x] = h_gate[b * H + threadIdx.x];
    sh[threadIdx.x + 512] = h_gate[b * H + threadIdx.x + 512];
    __syncthreads();
    int j = threadIdx.x;
    float acc = b1[j];
    for (int k = 0; k < H; ++k) acc = fmaf(sh[k], W1[(size_t)k * 512 + j], acc);
    float g = 0.5f * acc * (1.0f + erff(acc * 0.70710678118654752f));
    hid[b * 512 + j] = g;
}

// gamma[b,n] = sigmoid(hid[b,:] @ W2[:,n] + b2[n]).  grid(64) x 1024
__global__ void k_gate2(const float* __restrict__ hid, const float* __restrict__ W2,
                        const float* __restrict__ b2, float* __restrict__ gamma) {
    __shared__ float sh[512];
    int b = blockIdx.x;
    if (threadIdx.x < 512) sh[threadIdx.x] = hid[b * 512 + threadIdx.x];
    __syncthreads();
    int n = threadIdx.x;
    float acc = b2[n];
    for (int k = 0; k < 512; ++k) acc = fmaf(sh[k], W2[(size_t)k * Nn + n], acc);
    gamma[b * Nn + n] = 1.0f / (1.0f + expf(-acc));
}

// gmean[n] = mean_b gamma[b,n].  grid(4) x 256
__global__ void k_gmean(const float* __restrict__ gamma, float* __restrict__ gmean) {
    int n = blockIdx.x * 256 + threadIdx.x;
    float s = 0.f;
    for (int b = 0; b < Bb; ++b) s += gamma[b * Nn + n];
    gmean[n] = s * (1.0f / Bb);
}

// A_mix[i,j] = gmean[i] * (alpha*A_p[i,j] + (1-alpha)*0.5*S[i,j]*(inv_r[i]+inv_r[j]))
// grid(1024) x 256
__global__ void k_amix(const float* __restrict__ S, const float* __restrict__ A_p,
                       const float* __restrict__ inv_r, const float* __restrict__ gmean,
                       const float* __restrict__ alpha_raw, float* __restrict__ A_mix) {
    int i = blockIdx.x;
    float alpha = 1.0f / (1.0f + expf(-alpha_raw[0]));
    float gm = gmean[i];
    float iri = inv_r[i];
    #pragma unroll
    for (int q = 0; q < 4; ++q) {
        int j = threadIdx.x + 256 * q;
        size_t idx = (size_t)i * Nn + j;
        float ad = 0.5f * S[idx] * (iri + inv_r[j]);
        A_mix[idx] = gm * fmaf(alpha, A_p[idx], (1.0f - alpha) * ad);
    }
}

// bias_h[h] = sum_n h2n_b[n]*C1[n,h] + n2h_b[h].  grid(4) x 256
__global__ void k_biash(const float* __restrict__ h2n_b, const float* __restrict__ C1,
                        const float* __restrict__ n2h_b, float* __restrict__ bias_h) {
    int h = blockIdx.x * 256 + threadIdx.x;
    float s = n2h_b[h];
    for (int n = 0; n < Nn; ++n) s = fmaf(h2n_b[n], C1[(size_t)n * H + h], s);
    bias_h[h] = s;
}

// dst[j][i] = bf16(src[i][j]), 1024x1024.  grid(32,32) x 256 (32x8)
__global__ void k_trans_bf16(const float* __restrict__ src, unsigned short* __restrict__ dst) {
    __shared__ float tile[32][33];
    int i0 = blockIdx.y * 32, j0 = blockIdx.x * 32;
    int tx = threadIdx.x & 31, ty = threadIdx.x >> 5;  // 32 x 8
    #pragma unroll
    for (int q = 0; q < 4; ++q)
        tile[ty + 8 * q][tx] = src[(size_t)(i0 + ty + 8 * q) * 1024 + j0 + tx];
    __syncthreads();
    #pragma unroll
    for (int q = 0; q < 4; ++q)
        dst[(size_t)(j0 + ty + 8 * q) * 1024 + i0 + tx] = f2bf(tile[tx][ty + 8 * q]);
}

// ---------------- GEMM 64x64x16 fp32 (for 1024^3 chain GEMMs) ----------------
template <bool TA, bool TB, bool RELU>
__global__ __launch_bounds__(256) void gemm64(const float* __restrict__ A,
                                              const float* __restrict__ B,
                                              float* __restrict__ C,
                                              int M, int N, int K) {
    __shared__ float As[16][68];
    __shared__ float Bs[16][68];
    int tid = threadIdx.x;
    int n0 = blockIdx.x * 64, m0 = blockIdx.y * 64;
    int tx = tid & 15, ty = tid >> 4;
    float acc[4][4] = {};
    for (int k0 = 0; k0 < K; k0 += 16) {
        if (!TA) {
            int m = tid >> 2, k = (tid & 3) * 4;
            float4 v = *(const float4*)(A + (size_t)(m0 + m) * K + k0 + k);
            As[k + 0][m] = v.x; As[k + 1][m] = v.y; As[k + 2][m] = v.z; As[k + 3][m] = v.w;
        } else {
            int kk = tid >> 4, m = (tid & 15) * 4;
            float4 v = *(const float4*)(A + (size_t)(k0 + kk) * M + m0 + m);
            *(float4*)&As[kk][m] = v;
        }
        if (!TB) {
            int kk = tid >> 4, n = (tid & 15) * 4;
            float4 v = *(const float4*)(B + (size_t)(k0 + kk) * N + n0 + n);
            *(float4*)&Bs[kk][n] = v;
        } else {
            int n = tid >> 2, k = (tid & 3) * 4;
            float4 v = *(const float4*)(B + (size_t)(n0 + n) * K + k0 + k);
            Bs[k + 0][n] = v.x; Bs[k + 1][n] = v.y; Bs[k + 2][n] = v.z; Bs[k + 3][n] = v.w;
        }
        __syncthreads();
        #pragma unroll
        for (int k = 0; k < 16; ++k) {
            float a[4], b[4];
            #pragma unroll
            for (int i = 0; i < 4; ++i) a[i] = As[k][ty * 4 + i];
            #pragma unroll
            for (int j = 0; j < 4; ++j) b[j] = Bs[k][tx * 4 + j];
            #pragma unroll
            for (int i = 0; i < 4; ++i)
                #pragma unroll
                for (int j = 0; j < 4; ++j)
                    acc[i][j] = fmaf(a[i], b[j], acc[i][j]);
        }
        __syncthreads();
    }
    #pragma unroll
    for (int i = 0; i < 4; ++i) {
        int m = m0 + ty * 4 + i;
        float4 v;
        v.x = acc[i][0]; v.y = acc[i][1]; v.z = acc[i][2]; v.w = acc[i][3];
        if (RELU) {
            v.x = fmaxf(v.x, 0.f); v.y = fmaxf(v.y, 0.f);
            v.z = fmaxf(v.z, 0.f); v.w = fmaxf(v.w, 0.f);
        }
        *(float4*)(C + (size_t)m * N + n0 + tx * 4) = v;
    }
}

// ---------------- MFMA bf16 GEMM (m97 structure): C = A @ Bt^T + bias ----------------
// A: [M][K] bf16 row-major.  Bt: [N][K] bf16 row-major.  C: [M][N] fp32.
// 128x128 tile, 4 waves (2x2), each wave 4x4 of 16x16x32 MFMA, BK=32,
// global_load_lds width-16 staging.  M%128==0, N%128==0, K%32==0.
__global__ __launch_bounds__(256) void gemm_bt_mfma_bias(
    const unsigned short* __restrict__ A, const unsigned short* __restrict__ Bt,
    const float* __restrict__ bias, float* __restrict__ C, int M, int N, int K) {
    __shared__ unsigned short As[128 * 32];
    __shared__ unsigned short Bs[128 * 32];
    const int tid = threadIdx.x;
    const int wave = tid >> 6, lane = tid & 63;
    const int m0 = blockIdx.y * 128, n0 = blockIdx.x * 128;
    const int wm = (wave >> 1) * 64, wn = (wave & 1) * 64;
    const int quad = lane >> 4, l16 = lane & 15;

    f32x4 acc[4][4];
    #pragma unroll
    for (int i = 0; i < 4; ++i)
        #pragma unroll
        for (int j = 0; j < 4; ++j)
            acc[i][j] = (f32x4){0.f, 0.f, 0.f, 0.f};

    for (int k0 = 0; k0 < K; k0 += 32) {
        __syncthreads();   // prev iteration's LDS reads done before overwrite
        #pragma unroll
        for (int inst = 0; inst < 2; ++inst) {
            const int cbase = (wave * 2 + inst) * 64;
            const int c = cbase + lane;
            const int row = c >> 2, q = c & 3;  // row 0..127, 16B quarter of 64B row
            const unsigned short* ga = A + (size_t)(m0 + row) * K + k0 + q * 8;
            __builtin_amdgcn_global_load_lds(
                (const __attribute__((address_space(1))) unsigned int*)ga,
                (__attribute__((address_space(3))) unsigned int*)&As[cbase * 8], 16, 0, 0);
            const unsigned short* gb = Bt + (size_t)(n0 + row) * K + k0 + q * 8;
            __builtin_amdgcn_global_load_lds(
                (const __attribute__((address_space(1))) unsigned int*)gb,
                (__attribute__((address_space(3))) unsigned int*)&Bs[cbase * 8], 16, 0, 0);
        }
        __syncthreads();   // drain vmcnt: staged tile visible to all waves
        bf16x8 af[4], bfr[4];
        #pragma unroll
        for (int i = 0; i < 4; ++i) {
            af[i]  = *(const bf16x8*)&As[(wm + i * 16 + l16) * 32 + quad * 8];
            bfr[i] = *(const bf16x8*)&Bs[(wn + i * 16 + l16) * 32 + quad * 8];
        }
        #pragma unroll
        for (int i = 0; i < 4; ++i)
            #pragma unroll
            for (int j = 0; j < 4; ++j)
                acc[i][j] = __builtin_amdgcn_mfma_f32_16x16x32_bf16(af[i], bfr[j], acc[i][j], 0, 0, 0);
    }
    // epilogue: C[m][n] = acc + bias[n];  c/d layout: col=lane&15, row=quad*4+reg
    #pragma unroll
    for (int j = 0; j < 4; ++j) {
        const int n = n0 + wn + j * 16 + l16;
        const float bv = bias[n];
        #pragma unroll
        for (int i = 0; i < 4; ++i) {
            #pragma unroll
            for (int r = 0; r < 4; ++r) {
                const int m = m0 + wm + i * 16 + quad * 4 + r;
                C[(size_t)m * N + n] = acc[i][j][r] + bv;
            }
        }
    }
}

// ---------------- final: y = h_time*(1+tanh(1/N)) + msg; LayerNorm; in-place on out ----------------
__global__ void k_final_ln(const float* __restrict__ h_time, const float* __restrict__ ln_w,
                           const float* __restrict__ ln_b, float* __restrict__ out) {
    size_t row = blockIdx.x;
    const float gw = tanhf(1.0f / (float)Nn);
    const float scale = 1.0f + gw;
    float y[4];
    float s = 0.f;
    #pragma unroll
    for (int q = 0; q < 4; ++q) {
        int h = threadIdx.x + 256 * q;
        y[q] = fmaf(h_time[row * H + h], scale, out[row * H + h]);
        s += y[q];
    }
    float mu = block_reduce_sum_256(s) * (1.0f / H);
    float ss = 0.f;
    #pragma unroll
    for (int q = 0; q < 4; ++q) {
        float d = y[q] - mu;
        ss += d * d;
    }
    float var = block_reduce_sum_256(ss) * (1.0f / H);
    float rstd = rsqrtf(var + 1e-5f);
    #pragma unroll
    for (int q = 0; q < 4; ++q) {
        int h = threadIdx.x + 256 * q;
        out[row * H + h] = fmaf((y[q] - mu) * rstd, ln_w[h], ln_b[h]);
    }
}

// ---------------- launch ----------------

extern "C" void kernel_launch(void* const* d_in, const int* in_sizes, int n_in,
                              void* d_out, int out_size, void* d_ws, size_t ws_size,
                              hipStream_t stream) {
    const float* h_time    = (const float*)d_in[0];
    const float* A_p       = (const float*)d_in[1];
    const float* E_dyn     = (const float*)d_in[2];
    const float* alpha_raw = (const float*)d_in[3];
    // d_in[4] = tau_raw: unused (softmax over axis 0 makes node_attn.mean(0) == 1/N exactly)
    const float* gW1   = (const float*)d_in[5];
    const float* gb1   = (const float*)d_in[6];
    const float* gW2   = (const float*)d_in[7];
    const float* gb2   = (const float*)d_in[8];
    const float* h2n_W = (const float*)d_in[9];
    const float* h2n_b = (const float*)d_in[10];
    const float* n2h_W = (const float*)d_in[11];
    const float* n2h_b = (const float*)d_in[12];
    const float* ln_w  = (const float*)d_in[13];
    const float* ln_b  = (const float*)d_in[14];
    float* out = (float*)d_out;

    float* ws = (float*)d_ws;
    float* h_gate = ws;  ws += Bb * H;        // 64K
    float* h_mean = ws;  ws += H;
    float* E_cur  = ws;  ws += Nn * H;        // 1M
    float* S      = ws;  ws += Nn * Nn;       // 1M
    float* inv_r  = ws;  ws += Nn;
    float* hid    = ws;  ws += Bb * 512;
    float* gamma  = ws;  ws += Bb * Nn;
    float* gmean  = ws;  ws += Nn;
    float* A_mix  = ws;  ws += Nn * Nn;       // 1M
    float* C1     = ws;  ws += Nn * H;        // 1M
    float* C2     = ws;  ws += H * H;         // 1M
    float* bias_h = ws;  ws += H;
    unsigned short* C2t = (unsigned short*)ws;  ws += (H * H) / 2;         // bf16 [H][H]
    unsigned short* ht  = (unsigned short*)ws;  ws += ((size_t)BT * H) / 2; // bf16 [BT][H]

    // --- means + bf16 copy of h_time ---
    k_hgate<<<dim3(4, 64), 256, 0, stream>>>(h_time, h_gate, ht);
    k_hmean<<<4, 256, 0, stream>>>(h_gate, h_mean);

    // --- E path: E_cur, S = relu(E_cur E_cur^T), inv_r ---
    k_ecur<<<1024, 256, 0, stream>>>(E_dyn, h_mean, E_cur);
    gemm64<false, true, true><<<dim3(16, 16), 256, 0, stream>>>(E_cur, E_cur, S, Nn, Nn, H);
    k_invr<<<1024, 256, 0, stream>>>(S, inv_r);

    // --- gate MLP -> gamma_mean ---
    k_gate1<<<64, 512, 0, stream>>>(h_gate, gW1, gb1, hid);
    k_gate2<<<64, 1024, 0, stream>>>(hid, gW2, gb2, gamma);
    k_gmean<<<4, 256, 0, stream>>>(gamma, gmean);

    // --- A_mix ---
    k_amix<<<1024, 256, 0, stream>>>(S, A_p, inv_r, gmean, alpha_raw, A_mix);

    // --- collapsed weight chain: C1 = A_mix^T @ n2h_W; C2 = h2n_W @ C1 ---
    gemm64<true, false, false><<<dim3(16, 16), 256, 0, stream>>>(A_mix, n2h_W, C1, Nn, H, Nn);
    gemm64<false, false, false><<<dim3(16, 16), 256, 0, stream>>>(h2n_W, C1, C2, H, H, Nn);
    k_biash<<<4, 256, 0, stream>>>(h2n_b, C1, n2h_b, bias_h);

    // --- C2t = bf16(C2^T) for the MFMA B^T operand ---
    k_trans_bf16<<<dim3(32, 32), 256, 0, stream>>>(C2, C2t);

    // --- msg = h_time @ C2 + bias_h (MFMA bf16, written into d_out) ---
    gemm_bt_mfma_bias<<<dim3(8, 128), 256, 0, stream>>>(ht, C2t, bias_h, out, BT, H, H);

    // --- y = h_time*(1+tanh(1/N)) + msg; LayerNorm (in-place on out) ---
    k_final_ln<<<BT, 256, 0, stream>>>(h_time, ln_w, ln_b, out);
}

// Round 3
// 408.014 us; speedup vs baseline: 2.2355x; 1.3894x over previous
//
#include <hip/hip_runtime.h>
#include <math.h>

#define H 1024
#define Nn 1024
#define Bb 64
#define Tt 256
#define BT (Bb * Tt)   // 16384

typedef unsigned short ushort_t;
typedef __attribute__((ext_vector_type(8))) short bf16x8;
typedef __attribute__((ext_vector_type(4))) float f32x4;

// ---------------- helpers ----------------

__device__ __forceinline__ ushort_t f2bf(float x) {
    union { float f; unsigned u; } v; v.f = x;
    unsigned r = v.u + 0x7FFFu + ((v.u >> 16) & 1u);   // RNE
    return (ushort_t)(r >> 16);
}
__device__ __forceinline__ float bf2f(ushort_t h) {
    union { unsigned u; float f; } v; v.u = ((unsigned)h) << 16; return v.f;
}

__device__ __forceinline__ float block_reduce_sum_256(float v) {
    __shared__ float sbuf[4];
    __syncthreads();
    #pragma unroll
    for (int off = 32; off > 0; off >>= 1) v += __shfl_down(v, off, 64);
    int lane = threadIdx.x & 63, w = threadIdx.x >> 6;
    if (lane == 0) sbuf[w] = v;
    __syncthreads();
    if (threadIdx.x == 0) sbuf[0] = sbuf[0] + sbuf[1] + sbuf[2] + sbuf[3];
    __syncthreads();
    return sbuf[0];
}

// ---------------- small kernels ----------------

// h_gate[b,h] = mean_t h_time[b,t,h]; also emit bf16 copy of h_time.  grid(4,64) x 256
__global__ void k_hgate(const float* __restrict__ h_time, float* __restrict__ h_gate,
                        ushort_t* __restrict__ ht_bf16) {
    int b = blockIdx.y;
    int col = blockIdx.x * 256 + threadIdx.x;
    float s = 0.f;
    const size_t base = (size_t)b * Tt * H + col;
    for (int t = 0; t < Tt; ++t) {
        float v = h_time[base + (size_t)t * H];
        s += v;
        ht_bf16[base + (size_t)t * H] = f2bf(v);
    }
    h_gate[b * H + col] = s * (1.0f / Tt);
}

// h_mean[h] = mean_b h_gate[b,h].  grid(4) x 256
__global__ void k_hmean(const float* __restrict__ h_gate, float* __restrict__ h_mean) {
    int h = blockIdx.x * 256 + threadIdx.x;
    float s = 0.f;
    for (int b = 0; b < Bb; ++b) s += h_gate[b * H + h];
    h_mean[h] = s * (1.0f / Bb);
}

// E_b[n,:] = bf16(normalize(E_dyn[n,:] + h_mean)).  grid(1024) x 256
__global__ void k_ecur(const float* __restrict__ E_dyn, const float* __restrict__ h_mean,
                       ushort_t* __restrict__ E_b) {
    int n = blockIdx.x;
    float e[4]; float ss = 0.f;
    #pragma unroll
    for (int q = 0; q < 4; ++q) {
        int h = threadIdx.x + 256 * q;
        e[q] = E_dyn[(size_t)n * H + h] + h_mean[h];
        ss += e[q] * e[q];
    }
    float tot = block_reduce_sum_256(ss);
    float scale = 1.0f / fmaxf(sqrtf(tot), 1e-12f);
    #pragma unroll
    for (int q = 0; q < 4; ++q) {
        int h = threadIdx.x + 256 * q;
        E_b[(size_t)n * H + h] = f2bf(e[q] * scale);
    }
}

// hid[b,j] = gelu(h_gate[b,:] @ W1[:,j] + b1[j]).  grid(64) x 512
__global__ void k_gate1(const float* __restrict__ h_gate, const float* __restrict__ W1,
                        const float* __restrict__ b1, float* __restrict__ hid) {
    __shared__ float sh[H];
    int b = blockIdx.x;
    sh[threadIdx.x] = h_gate[b * H + threadIdx.x];
    sh[threadIdx.x + 512] = h_gate[b * H + threadIdx.x + 512];
    __syncthreads();
    int j = threadIdx.x;
    float acc = b1[j];
    for (int k = 0; k < H; ++k) acc = fmaf(sh[k], W1[(size_t)k * 512 + j], acc);
    float g = 0.5f * acc * (1.0f + erff(acc * 0.70710678118654752f));
    hid[b * 512 + j] = g;
}

// gamma[b,n] = sigmoid(hid[b,:] @ W2[:,n] + b2[n]).  grid(64) x 1024
__global__ void k_gate2(const float* __restrict__ hid, const float* __restrict__ W2,
                        const float* __restrict__ b2, float* __restrict__ gamma) {
    __shared__ float sh[512];
    int b = blockIdx.x;
    if (threadIdx.x < 512) sh[threadIdx.x] = hid[b * 512 + threadIdx.x];
    __syncthreads();
    int n = threadIdx.x;
    float acc = b2[n];
    for (int k = 0; k < 512; ++k) acc = fmaf(sh[k], W2[(size_t)k * Nn + n], acc);
    gamma[b * Nn + n] = 1.0f / (1.0f + expf(-acc));
}

// gmean[n] = mean_b gamma[b,n].  grid(4) x 256
__global__ void k_gmean(const float* __restrict__ gamma, float* __restrict__ gmean) {
    int n = blockIdx.x * 256 + threadIdx.x;
    float s = 0.f;
    for (int b = 0; b < Bb; ++b) s += gamma[b * Nn + n];
    gmean[n] = s * (1.0f / Bb);
}

// sum 4 split-K partials of E E^T, relu, write S fp32 + inv_r.  grid(1024) x 256
__global__ void k_reduce_relu_rowsum(const float* __restrict__ P, float* __restrict__ S,
                                     float* __restrict__ inv_r) {
    int row = blockIdx.x;
    const size_t MN = (size_t)Nn * Nn;
    size_t base = (size_t)row * Nn + threadIdx.x * 4;
    float4 a0 = *(const float4*)&P[base];
    float4 a1 = *(const float4*)&P[base + MN];
    float4 a2 = *(const float4*)&P[base + 2 * MN];
    float4 a3 = *(const float4*)&P[base + 3 * MN];
    float4 s4;
    s4.x = fmaxf(a0.x + a1.x + a2.x + a3.x, 0.f);
    s4.y = fmaxf(a0.y + a1.y + a2.y + a3.y, 0.f);
    s4.z = fmaxf(a0.z + a1.z + a2.z + a3.z, 0.f);
    s4.w = fmaxf(a0.w + a1.w + a2.w + a3.w, 0.f);
    *(float4*)&S[base] = s4;
    float tot = block_reduce_sum_256(s4.x + s4.y + s4.z + s4.w);
    if (threadIdx.x == 0) inv_r[row] = 1.0f / (tot + 1e-6f);
}

// A_mix transposed + hi/lo bf16 split.  A_mixT[j][i] = A_mix[i][j].  grid(32,32) x 256
__global__ void k_amix_t(const float* __restrict__ S, const float* __restrict__ A_p,
                         const float* __restrict__ inv_r, const float* __restrict__ gmean,
                         const float* __restrict__ alpha_raw,
                         ushort_t* __restrict__ Th, ushort_t* __restrict__ Tl) {
    __shared__ float tile[32][33];
    int i0 = blockIdx.y * 32, j0 = blockIdx.x * 32;
    int tx = threadIdx.x & 31, ty = threadIdx.x >> 5;
    float alpha = 1.0f / (1.0f + expf(-alpha_raw[0]));
    #pragma unroll
    for (int q = 0; q < 4; ++q) {
        int i = i0 + ty + 8 * q, j = j0 + tx;
        size_t idx = (size_t)i * Nn + j;
        float ad = 0.5f * S[idx] * (inv_r[i] + inv_r[j]);
        tile[ty + 8 * q][tx] = gmean[i] * fmaf(alpha, A_p[idx], (1.0f - alpha) * ad);
    }
    __syncthreads();
    #pragma unroll
    for (int q = 0; q < 4; ++q) {
        float v = tile[tx][ty + 8 * q];
        size_t o = (size_t)(j0 + ty + 8 * q) * Nn + i0 + tx;
        ushort_t h = f2bf(v);
        Th[o] = h;
        Tl[o] = f2bf(v - bf2f(h));
    }
}

// transpose fp32 src -> hi/lo bf16 dstT.  grid(32,32) x 256
__global__ void k_trans_split(const float* __restrict__ src,
                              ushort_t* __restrict__ Th, ushort_t* __restrict__ Tl) {
    __shared__ float tile[32][33];
    int i0 = blockIdx.y * 32, j0 = blockIdx.x * 32;
    int tx = threadIdx.x & 31, ty = threadIdx.x >> 5;
    #pragma unroll
    for (int q = 0; q < 4; ++q)
        tile[ty + 8 * q][tx] = src[(size_t)(i0 + ty + 8 * q) * Nn + j0 + tx];
    __syncthreads();
    #pragma unroll
    for (int q = 0; q < 4; ++q) {
        float v = tile[tx][ty + 8 * q];
        size_t o = (size_t)(j0 + ty + 8 * q) * Nn + i0 + tx;
        ushort_t h = f2bf(v);
        Th[o] = h;
        Tl[o] = f2bf(v - bf2f(h));
    }
}

// elementwise fp32 -> hi/lo bf16.  grid(1024) x 256 (4 elems/thread)
__global__ void k_split(const float* __restrict__ src,
                        ushort_t* __restrict__ Dh, ushort_t* __restrict__ Dl) {
    size_t idx = ((size_t)blockIdx.x * 256 + threadIdx.x) * 4;
    float4 v = *(const float4*)&src[idx];
    union { ushort_t u[4]; uint2 w; } ph, pl;
    float c[4] = {v.x, v.y, v.z, v.w};
    #pragma unroll
    for (int q = 0; q < 4; ++q) {
        ph.u[q] = f2bf(c[q]);
        pl.u[q] = f2bf(c[q] - bf2f(ph.u[q]));
    }
    *(uint2*)&Dh[idx] = ph.w;
    *(uint2*)&Dl[idx] = pl.w;
}

// sum 4 partials -> fp32 + hi/lo bf16.  grid(1024) x 256
__global__ void k_reduce_split(const float* __restrict__ P, float* __restrict__ Cf,
                               ushort_t* __restrict__ Ch, ushort_t* __restrict__ Cl) {
    size_t idx = ((size_t)blockIdx.x * 256 + threadIdx.x) * 4;
    const size_t MN = (size_t)Nn * H;
    float4 a0 = *(const float4*)&P[idx];
    float4 a1 = *(const float4*)&P[idx + MN];
    float4 a2 = *(const float4*)&P[idx + 2 * MN];
    float4 a3 = *(const float4*)&P[idx + 3 * MN];
    float c[4] = {a0.x + a1.x + a2.x + a3.x, a0.y + a1.y + a2.y + a3.y,
                  a0.z + a1.z + a2.z + a3.z, a0.w + a1.w + a2.w + a3.w};
    *(float4*)&Cf[idx] = *(float4*)c;
    union { ushort_t u[4]; uint2 w; } ph, pl;
    #pragma unroll
    for (int q = 0; q < 4; ++q) {
        ph.u[q] = f2bf(c[q]);
        pl.u[q] = f2bf(c[q] - bf2f(ph.u[q]));
    }
    *(uint2*)&Ch[idx] = ph.w;
    *(uint2*)&Cl[idx] = pl.w;
}

// sum 4 partials -> single bf16.  grid(1024) x 256
__global__ void k_reduce_bf16(const float* __restrict__ P, ushort_t* __restrict__ Cb) {
    size_t idx = ((size_t)blockIdx.x * 256 + threadIdx.x) * 4;
    const size_t MN = (size_t)Nn * H;
    float4 a0 = *(const float4*)&P[idx];
    float4 a1 = *(const float4*)&P[idx + MN];
    float4 a2 = *(const float4*)&P[idx + 2 * MN];
    float4 a3 = *(const float4*)&P[idx + 3 * MN];
    union { ushort_t u[4]; uint2 w; } pb;
    pb.u[0] = f2bf(a0.x + a1.x + a2.x + a3.x);
    pb.u[1] = f2bf(a0.y + a1.y + a2.y + a3.y);
    pb.u[2] = f2bf(a0.z + a1.z + a2.z + a3.z);
    pb.u[3] = f2bf(a0.w + a1.w + a2.w + a3.w);
    *(uint2*)&Cb[idx] = pb.w;
}

// bias_h[h] = sum_n h2n_b[n]*C1T[h][n] + n2h_b[h].  grid(256) x 256, wave per row
__global__ void k_biash_gemv(const float* __restrict__ h2n_b, const float* __restrict__ C1T,
                             const float* __restrict__ n2h_b, float* __restrict__ bias_h) {
    int lane = threadIdx.x & 63, wave = threadIdx.x >> 6;
    int row = blockIdx.x * 4 + wave;
    float s = 0.f;
    #pragma unroll
    for (int q = 0; q < 4; ++q) {
        int k = lane * 16 + q * 4;
        float4 a = *(const float4*)&C1T[(size_t)row * Nn + k];
        float4 b = *(const float4*)&h2n_b[k];
        s += a.x * b.x + a.y * b.y + a.z * b.z + a.w * b.w;
    }
    #pragma unroll
    for (int off = 32; off > 0; off >>= 1) s += __shfl_down(s, off, 64);
    if (lane == 0) bias_h[row] = s + n2h_b[row];
}

// ---------------- MFMA bf16 GEMM, m97 structure, optional 3-pass hi/lo split ----------------
// C = Ah@Bh^T (+ Ah@Bl^T + Al@Bh^T if PASSES==3) (+ bias[n] if BIAS)
// SPLITK: grid(N/128, M/128, KZ), block kz handles k in [kz*kchunk, kz*kchunk+kchunk),
//         writes partial to C + kz*M*N.
// !SPLITK: grid 1D M/128*N/128 with XCD swizzle, kchunk == K.
template <int PASSES, bool SPLITK, bool BIAS>
__global__ __launch_bounds__(256) void gemm_bt_mfma(
    const ushort_t* __restrict__ Ah, const ushort_t* __restrict__ Al,
    const ushort_t* __restrict__ Bh, const ushort_t* __restrict__ Bl,
    const float* __restrict__ bias, float* __restrict__ C,
    int M, int N, int K, int kchunk) {
    __shared__ ushort_t sAh[128 * 32];
    __shared__ ushort_t sBh[128 * 32];
    __shared__ ushort_t sAl[PASSES == 3 ? 128 * 32 : 8];
    __shared__ ushort_t sBl[PASSES == 3 ? 128 * 32 : 8];
    __shared__ float Es[4][16][80];   // epilogue transpose, per-wave region

    const int tid = threadIdx.x;
    const int wave = tid >> 6, lane = tid & 63;
    const int quad = lane >> 4, l16 = lane & 15;
    int m0, n0, kz;
    if (SPLITK) {
        m0 = blockIdx.y * 128; n0 = blockIdx.x * 128; kz = blockIdx.z;
    } else {
        int bx = blockIdx.x;               // XCD swizzle: same-A-panel blocks -> same XCD
        int g = bx & 7, s = bx >> 3;
        m0 = (g * 16 + (s >> 3)) * 128;
        n0 = (s & 7) * 128;
        kz = 0;
    }
    const int kbeg = kz * kchunk, kend = kbeg + kchunk;
    float* Cw = SPLITK ? (C + (size_t)kz * M * N) : C;
    const int wm = (wave >> 1) * 64, wn = (wave & 1) * 64;

    f32x4 acc[4][4];
    #pragma unroll
    for (int i = 0; i < 4; ++i)
        #pragma unroll
        for (int j = 0; j < 4; ++j)
            acc[i][j] = (f32x4){0.f, 0.f, 0.f, 0.f};

    for (int k0 = kbeg; k0 < kend; k0 += 32) {
        __syncthreads();
        #pragma unroll
        for (int inst = 0; inst < 2; ++inst) {
            const int cbase = (wave * 2 + inst) * 64;
            const int c = cbase + lane;
            const int row = c >> 2, q = c & 3;
            const size_t offA = (size_t)(m0 + row) * K + k0 + q * 8;
            const size_t offB = (size_t)(n0 + row) * K + k0 + q * 8;
            __builtin_amdgcn_global_load_lds(
                (const __attribute__((address_space(1))) unsigned int*)(Ah + offA),
                (__attribute__((address_space(3))) unsigned int*)&sAh[cbase * 8], 16, 0, 0);
            __builtin_amdgcn_global_load_lds(
                (const __attribute__((address_space(1))) unsigned int*)(Bh + offB),
                (__attribute__((address_space(3))) unsigned int*)&sBh[cbase * 8], 16, 0, 0);
            if constexpr (PASSES == 3) {
                __builtin_amdgcn_global_load_lds(
                    (const __attribute__((address_space(1))) unsigned int*)(Al + offA),
                    (__attribute__((address_space(3))) unsigned int*)&sAl[cbase * 8], 16, 0, 0);
                __builtin_amdgcn_global_load_lds(
                    (const __attribute__((address_space(1))) unsigned int*)(Bl + offB),
                    (__attribute__((address_space(3))) unsigned int*)&sBl[cbase * 8], 16, 0, 0);
            }
        }
        __syncthreads();
        bf16x8 fah[4], fbh[4];
        bf16x8 fal[PASSES == 3 ? 4 : 1], fbl[PASSES == 3 ? 4 : 1];
        #pragma unroll
        for (int i = 0; i < 4; ++i) {
            fah[i] = *(const bf16x8*)&sAh[(wm + i * 16 + l16) * 32 + quad * 8];
            fbh[i] = *(const bf16x8*)&sBh[(wn + i * 16 + l16) * 32 + quad * 8];
            if constexpr (PASSES == 3) {
                fal[i] = *(const bf16x8*)&sAl[(wm + i * 16 + l16) * 32 + quad * 8];
                fbl[i] = *(const bf16x8*)&sBl[(wn + i * 16 + l16) * 32 + quad * 8];
            }
        }
        #pragma unroll
        for (int i = 0; i < 4; ++i)
            #pragma unroll
            for (int j = 0; j < 4; ++j) {
                acc[i][j] = __builtin_amdgcn_mfma_f32_16x16x32_bf16(fah[i], fbh[j], acc[i][j], 0, 0, 0);
                if constexpr (PASSES == 3) {
                    acc[i][j] = __builtin_amdgcn_mfma_f32_16x16x32_bf16(fah[i], fbl[j], acc[i][j], 0, 0, 0);
                    acc[i][j] = __builtin_amdgcn_mfma_f32_16x16x32_bf16(fal[i], fbh[j], acc[i][j], 0, 0, 0);
                }
            }
    }
    // epilogue: per-wave LDS transpose -> coalesced float4 stores
    float bv[4];
    if (BIAS) {
        #pragma unroll
        for (int j = 0; j < 4; ++j) bv[j] = bias[n0 + wn + j * 16 + l16];
    }
    #pragma unroll
    for (int i = 0; i < 4; ++i) {
        #pragma unroll
        for (int j = 0; j < 4; ++j)
            #pragma unroll
            for (int r = 0; r < 4; ++r)
                Es[wave][quad * 4 + r][j * 16 + l16] = acc[i][j][r] + (BIAS ? bv[j] : 0.f);
        __syncthreads();
        #pragma unroll
        for (int it = 0; it < 4; ++it) {
            int idx = it * 64 + lane;
            int row = idx >> 4, f4 = idx & 15;
            float4 v = *(const float4*)&Es[wave][row][f4 * 4];
            *(float4*)&Cw[(size_t)(m0 + wm + i * 16 + row) * N + n0 + wn + f4 * 4] = v;
        }
        __syncthreads();
    }
}

// ---------------- final: y = h_time*(1+tanh(1/N)) + msg; LayerNorm in-place ----------------
__global__ void k_final_ln(const float* __restrict__ h_time, const float* __restrict__ ln_w,
                           const float* __restrict__ ln_b, float* __restrict__ out) {
    size_t row = blockIdx.x;
    const float scale = 1.0f + tanhf(1.0f / (float)Nn);
    float y[4];
    float s = 0.f;
    #pragma unroll
    for (int q = 0; q < 4; ++q) {
        int h = threadIdx.x + 256 * q;
        y[q] = fmaf(h_time[row * H + h], scale, out[row * H + h]);
        s += y[q];
    }
    float mu = block_reduce_sum_256(s) * (1.0f / H);
    float ss = 0.f;
    #pragma unroll
    for (int q = 0; q < 4; ++q) { float d = y[q] - mu; ss += d * d; }
    float var = block_reduce_sum_256(ss) * (1.0f / H);
    float rstd = rsqrtf(var + 1e-5f);
    #pragma unroll
    for (int q = 0; q < 4; ++q) {
        int h = threadIdx.x + 256 * q;
        out[row * H + h] = fmaf((y[q] - mu) * rstd, ln_w[h], ln_b[h]);
    }
}

// ---------------- launch ----------------

extern "C" void kernel_launch(void* const* d_in, const int* in_sizes, int n_in,
                              void* d_out, int out_size, void* d_ws, size_t ws_size,
                              hipStream_t stream) {
    const float* h_time    = (const float*)d_in[0];
    const float* A_p       = (const float*)d_in[1];
    const float* E_dyn     = (const float*)d_in[2];
    const float* alpha_raw = (const float*)d_in[3];
    // d_in[4] = tau_raw: unused (softmax over axis 0 => node_attn.mean(0) == 1/N exactly)
    const float* gW1   = (const float*)d_in[5];
    const float* gb1   = (const float*)d_in[6];
    const float* gW2   = (const float*)d_in[7];
    const float* gb2   = (const float*)d_in[8];
    const float* h2n_W = (const float*)d_in[9];
    const float* h2n_b = (const float*)d_in[10];
    const float* n2h_W = (const float*)d_in[11];
    const float* n2h_b = (const float*)d_in[12];
    const float* ln_w  = (const float*)d_in[13];
    const float* ln_b  = (const float*)d_in[14];
    float* out = (float*)d_out;
    float* P = out;                       // split-K partial scratch (4 MB*4), overwritten later

    float* ws = (float*)d_ws;
    float* h_gate = ws;  ws += Bb * H;
    float* h_mean = ws;  ws += H;
    float* hid    = ws;  ws += Bb * 512;
    float* gamma  = ws;  ws += Bb * Nn;
    float* gmean  = ws;  ws += Nn;
    float* inv_r  = ws;  ws += Nn;
    float* bias_h = ws;  ws += H;
    ws += 256;                             // pad/align
    float* S      = ws;  ws += Nn * Nn;    // 4 MB
    float* C1T    = ws;  ws += H * Nn;     // 4 MB
    ushort_t* E_b     = (ushort_t*)ws;  ws += (Nn * H) / 2;
    ushort_t* AmixT_h = (ushort_t*)ws;  ws += (Nn * Nn) / 2;
    ushort_t* AmixT_l = (ushort_t*)ws;  ws += (Nn * Nn) / 2;
    ushort_t* n2hWT_h = (ushort_t*)ws;  ws += (Nn * H) / 2;
    ushort_t* n2hWT_l = (ushort_t*)ws;  ws += (Nn * H) / 2;
    ushort_t* h2nW_h  = (ushort_t*)ws;  ws += (H * Nn) / 2;
    ushort_t* h2nW_l  = (ushort_t*)ws;  ws += (H * Nn) / 2;
    ushort_t* C1T_h   = (ushort_t*)ws;  ws += (H * Nn) / 2;
    ushort_t* C1T_l   = (ushort_t*)ws;  ws += (H * Nn) / 2;
    ushort_t* C2t     = (ushort_t*)ws;  ws += (H * H) / 2;
    ushort_t* ht      = (ushort_t*)ws;  ws += ((size_t)BT * H) / 2;

    // means + bf16 h_time
    k_hgate<<<dim3(4, 64), 256, 0, stream>>>(h_time, h_gate, ht);
    k_hmean<<<4, 256, 0, stream>>>(h_gate, h_mean);
    k_ecur<<<1024, 256, 0, stream>>>(E_dyn, h_mean, E_b);

    // gate MLP -> gmean
    k_gate1<<<64, 512, 0, stream>>>(h_gate, gW1, gb1, hid);
    k_gate2<<<64, 1024, 0, stream>>>(hid, gW2, gb2, gamma);
    k_gmean<<<4, 256, 0, stream>>>(gamma, gmean);

    // S = relu(E E^T) via bf16 MFMA split-K=4 (A_dyn is ~0.1% of A_mix: bf16 is plenty)
    gemm_bt_mfma<1, true, false><<<dim3(8, 8, 4), 256, 0, stream>>>(
        E_b, nullptr, E_b, nullptr, nullptr, P, Nn, Nn, H, 256);
    k_reduce_relu_rowsum<<<1024, 256, 0, stream>>>(P, S, inv_r);

    // A_mix^T hi/lo; n2h_W^T hi/lo; h2n_W hi/lo
    k_amix_t<<<dim3(32, 32), 256, 0, stream>>>(S, A_p, inv_r, gmean, alpha_raw, AmixT_h, AmixT_l);
    k_trans_split<<<dim3(32, 32), 256, 0, stream>>>(n2h_W, n2hWT_h, n2hWT_l);
    k_split<<<1024, 256, 0, stream>>>(h2n_W, h2nW_h, h2nW_l);

    // C1T[h][n] = sum_k n2h_W[k][h] * A_mix[k][n]   (3-pass split bf16, fp32-class accuracy)
    gemm_bt_mfma<3, true, false><<<dim3(8, 8, 4), 256, 0, stream>>>(
        n2hWT_h, n2hWT_l, AmixT_h, AmixT_l, nullptr, P, Nn, Nn, Nn, 256);
    k_reduce_split<<<1024, 256, 0, stream>>>(P, C1T, C1T_h, C1T_l);

    // C2t[h'][h] = sum_n C1T[h'][n] * h2n_W[h][n]  ( = C2^T, the big GEMM's B operand )
    gemm_bt_mfma<3, true, false><<<dim3(8, 8, 4), 256, 0, stream>>>(
        C1T_h, C1T_l, h2nW_h, h2nW_l, nullptr, P, Nn, Nn, Nn, 256);
    k_reduce_bf16<<<1024, 256, 0, stream>>>(P, C2t);

    // bias_h = h2n_b @ C1 + n2h_b  (row-coalesced gemv over C1T)
    k_biash_gemv<<<256, 256, 0, stream>>>(h2n_b, C1T, n2h_b, bias_h);

    // msg = h_time @ C2 + bias_h  (overwrites the partial scratch in d_out)
    gemm_bt_mfma<1, false, true><<<1024, 256, 0, stream>>>(
        ht, nullptr, C2t, nullptr, bias_h, out, BT, H, H, H);

    // y = h_time*(1+tanh(1/N)) + msg; LayerNorm
    k_final_ln<<<BT, 256, 0, stream>>>(h_time, ln_w, ln_b, out);
}